// Round 9
// baseline (188.710 us; speedup 1.0000x reference)
//
#include <hip/hip_runtime.h>
#include <math.h>

#define B_  2
#define T_  2048
#define D_  1024
#define H_  16
#define HS_ 64
#define M_  (B_*T_)   // 4096

typedef __bf16 bf16x8 __attribute__((ext_vector_type(8)));
typedef float  f32x4  __attribute__((ext_vector_type(4)));
typedef unsigned short u16;

// native HW cvt — RNE, 1 inst (packs) vs 3-4 manual
static __device__ __forceinline__ u16 f2bf(float f) {
    __bf16 h = (__bf16)f;
    return *reinterpret_cast<u16*>(&h);
}

// async global->LDS, 16B/lane; LDS dest is lane-linear (base + lane*16).
static __device__ __forceinline__ void glds16(const u16* g, u16* l) {
    __builtin_amdgcn_global_load_lds(
        (const __attribute__((address_space(1))) void*)g,
        (__attribute__((address_space(3))) void*)l, 16, 0, 0);
}

// 4-chunk-row swizzle (BK=32 rows = 4 x 16B chunks):
// chunk c of row r lives at slot r*4 + (c ^ ((r>>1)&3)) — conflict-free.
static __device__ __forceinline__ bf16x8 lds_chunk4(const u16* base, int row, int c) {
    return *reinterpret_cast<const bf16x8*>(base + (size_t)(row * 4 + (c ^ ((row >> 1) & 3))) * 8);
}

// ---------------- fused prep: cast x, transpose+cast both weights ----------
__global__ __launch_bounds__(256) void prep_kernel(
    const float* __restrict__ x, const float* __restrict__ w_qkv,
    const float* __restrict__ w_out,
    u16* __restrict__ Xb, u16* __restrict__ WqkvT, u16* __restrict__ WoutT)
{
    int bid = blockIdx.x;
    if (bid < 4096) {                       // cast x
        int i = (bid * 256 + threadIdx.x) * 4;
        float4 v = *reinterpret_cast<const float4*>(x + i);
        ushort4 o;
        o.x = f2bf(v.x); o.y = f2bf(v.y); o.z = f2bf(v.z); o.w = f2bf(v.w);
        *reinterpret_cast<ushort4*>(Xb + i) = o;
        return;
    }
    const float* in; u16* out; int C; int c0, r0;
    if (bid < 4096 + 3072) {                // w_qkv (D x 3D) -> (3D x D)
        int t = bid - 4096;
        in = w_qkv; out = WqkvT; C = 3 * D_;
        c0 = (t % 96) * 32; r0 = (t / 96) * 32;
    } else {                                // w_out (D x D) -> (D x D)
        int t = bid - 7168;
        in = w_out; out = WoutT; C = D_;
        c0 = (t & 31) * 32; r0 = (t >> 5) * 32;
    }
    __shared__ float tile[32][33];
    int tr = threadIdx.x >> 3, tc4 = (threadIdx.x & 7) * 4;
    float4 v = *reinterpret_cast<const float4*>(in + (size_t)(r0 + tr) * C + c0 + tc4);
    tile[tr][tc4+0] = v.x; tile[tr][tc4+1] = v.y;
    tile[tr][tc4+2] = v.z; tile[tr][tc4+3] = v.w;
    __syncthreads();
    ushort4 o;
    o.x = f2bf(tile[tc4+0][tr]); o.y = f2bf(tile[tc4+1][tr]);
    o.z = f2bf(tile[tc4+2][tr]); o.w = f2bf(tile[tc4+3][tr]);
    *reinterpret_cast<ushort4*>(out + (size_t)(c0 + tr) * D_ + r0 + tc4) = o;
}

// ---------------- GEMM: C(MxN) = A(MxK) @ Bt(NxK)^T + bias ----------------
template<int MODE>
__global__ __launch_bounds__(256) void gemm_bt(
    const u16* __restrict__ A, const u16* __restrict__ Bt,
    const float* __restrict__ bias,
    float* __restrict__ Cf,
    u16* __restrict__ Qb, u16* __restrict__ Kb, u16* __restrict__ Vt,
    int M, int N, int K)
{
    __shared__ u16 As[128 * 32];   // swizzled chunk slots, 8 KB
    __shared__ u16 Bs[128 * 32];
    int tid  = threadIdx.x;
    int lane = tid & 63, wave = tid >> 6;
    int wm = wave >> 1, wn = wave & 1;
    int quad = lane >> 4, lr = lane & 15;
    int bm = blockIdx.x, bn = blockIdx.y;

    f32x4 acc[4][4] = {};

    const u16* Ab = A  + (size_t)(bm * 128) * K;
    const u16* Bb = Bt + (size_t)(bn * 128) * K;

    int r0 = tid >> 2,         c0 = (((tid) & 3) ^ ((tid >> 3) & 3)) * 8;
    int r1 = (tid + 256) >> 2, c1 = (((tid + 256) & 3) ^ (((tid + 256) >> 3) & 3)) * 8;

    for (int k0 = 0; k0 < K; k0 += 32) {
        __syncthreads();
        glds16(Ab + (size_t)r0 * K + k0 + c0, As + (size_t)tid * 8);
        glds16(Ab + (size_t)r1 * K + k0 + c1, As + (size_t)(tid + 256) * 8);
        glds16(Bb + (size_t)r0 * K + k0 + c0, Bs + (size_t)tid * 8);
        glds16(Bb + (size_t)r1 * K + k0 + c1, Bs + (size_t)(tid + 256) * 8);
        __syncthreads();
        bf16x8 af[4], bfr[4];
        #pragma unroll
        for (int i = 0; i < 4; ++i)
            af[i] = lds_chunk4(As, wm*64 + i*16 + lr, quad);
        #pragma unroll
        for (int j = 0; j < 4; ++j)
            bfr[j] = lds_chunk4(Bs, wn*64 + j*16 + lr, quad);
        #pragma unroll
        for (int i = 0; i < 4; ++i)
            #pragma unroll
            for (int j = 0; j < 4; ++j)
                acc[i][j] = __builtin_amdgcn_mfma_f32_16x16x32_bf16(af[i], bfr[j], acc[i][j], 0, 0, 0);
    }

    #pragma unroll
    for (int i = 0; i < 4; ++i) {
        int m0 = bm*128 + wm*64 + i*16 + quad*4;   // 4-aligned
        #pragma unroll
        for (int j = 0; j < 4; ++j) {
            int ncol = bn*128 + wn*64 + j*16 + lr;
            float bv = bias[ncol];
            float v4[4];
            #pragma unroll
            for (int r = 0; r < 4; ++r) v4[r] = acc[i][j][r] + bv;
            if (MODE == 1) {
                #pragma unroll
                for (int r = 0; r < 4; ++r)
                    Cf[(size_t)(m0 + r) * N + ncol] = v4[r];
            } else {
                int b = m0 >> 11, t0 = m0 & (T_ - 1);
                int s = ncol >> 10, rem = ncol & 1023;
                int h = rem >> 6, d = rem & 63;
                int bh = b * H_ + h;
                if (s == 0) {
                    // fold softmax scale AND log2(e) (attn uses exp2): 0.125*log2e
                    #pragma unroll
                    for (int r = 0; r < 4; ++r)
                        Qb[((size_t)bh*T_ + t0 + r)*HS_ + d] = f2bf(v4[r] * 0.1803368801111244f);
                } else if (s == 1) {
                    #pragma unroll
                    for (int r = 0; r < 4; ++r)
                        Kb[((size_t)bh*T_ + t0 + r)*HS_ + d] = f2bf(v4[r]);
                } else {
                    ushort4 o;   // consecutive t -> one 8B store
                    o.x = f2bf(v4[0]); o.y = f2bf(v4[1]);
                    o.z = f2bf(v4[2]); o.w = f2bf(v4[3]);
                    *reinterpret_cast<ushort4*>(&Vt[((size_t)bh*HS_ + d)*T_ + t0]) = o;
                }
            }
        }
    }
}

// ---------------- Flash attention (causal), bf16 MFMA ----------------
// R8 structure + single-barrier double-buffered K/V:
//   iter j: (1) issue next-tile global loads (regs),   <- in flight during (2)
//           (2) full QK^T / softmax / PV compute from buf=j&1,
//           (3) ds_write regs -> buf^1, one __syncthreads().
// Staging is register-based (not global_load_lds), so the loads legitimately
// overlap the compute phase — the vmcnt wait sits at the ds_write, after the
// MFMAs, not at a barrier before them. LDS 40 KB -> 4 blocks/CU (grid-capped
// at 4 anyway: no occupancy loss, half the barriers).
__global__ __launch_bounds__(256) void attn_kernel(
    const u16* __restrict__ Qb, const u16* __restrict__ Kb,
    const u16* __restrict__ Vt, u16* __restrict__ Ob)
{
    __shared__ u16 Ks[2][64 * 64];     // [buf][key][d], swizzled, 8 KB each
    __shared__ u16 Vs[2][64 * 64];     // [buf][d][key], swizzled, 8 KB each
    __shared__ u16 Ps[4][16 * 64];     // per-wave P (16 q x 64 key), swizzled

    int tid  = threadIdx.x;
    int lane = tid & 63, wave = tid >> 6;          // wave 0..3
    int quad = lane >> 4, lr = lane & 15;

    int lin = blockIdx.x;                          // 1024 blocks
    int bh  = (lin & 7) + 8 * ((lin >> 3) & 3);    // XCD-local bh
    int idx = lin >> 5;                            // 0..31
    int qt  = idx < 16 ? idx : 47 - idx;           // balanced pair mapping
    int qw  = qt * 64 + wave * 16;                 // wave's 16 query rows

    // Q fragments (A-layout); 1/sqrt(HS)*log2e pre-folded upstream
    const u16* Qp = Qb + ((size_t)bh * T_ + qw) * HS_;
    bf16x8 qf[2];
    #pragma unroll
    for (int h2 = 0; h2 < 2; ++h2)
        qf[h2] = *reinterpret_cast<const bf16x8*>(Qp + lr*HS_ + h2*32 + quad*8);

    f32x4 Oa[4] = {};
    float lrow[4] = {0.f, 0.f, 0.f, 0.f};

    // ---- loop-invariant LDS addresses (u16-element offsets) ----
    int e   = quad ^ (lr & 7);
    int rb0 = (lr * 8 + e) * 8;          // kk=0 chunk base
    int rb1 = (lr * 8 + (e ^ 4)) * 8;    // kk=1 chunk base
    int offw[4][4];
    #pragma unroll
    for (int nt = 0; nt < 4; ++nt)
        #pragma unroll
        for (int r = 0; r < 4; ++r) {
            int prow = quad*4 + r;
            offw[nt][r] = (prow*8 + ((nt*2 + (lr >> 3)) ^ (prow & 7)))*8 + (lr & 7);
        }
    u16* Psw = Ps[wave];

    // staging: 256 thr x 2 chunks per matrix; swizzle via source redirect
    int srow = tid >> 3;
    int scol = ((tid & 7) ^ (srow & 7)) * 8;
    const u16* kp0 = Kb + ((size_t)bh*T_ + srow     )*HS_ + scol;
    const u16* kp1 = Kb + ((size_t)bh*T_ + srow + 32)*HS_ + scol;
    const u16* vp0 = Vt + ((size_t)bh*HS_ + srow     )*T_ + scol;
    const u16* vp1 = Vt + ((size_t)bh*HS_ + srow + 32)*T_ + scol;

    // prologue: tile 0 -> buf 0
    {
        bf16x8 k0 = *reinterpret_cast<const bf16x8*>(kp0);
        bf16x8 k1 = *reinterpret_cast<const bf16x8*>(kp1);
        bf16x8 v0 = *reinterpret_cast<const bf16x8*>(vp0);
        bf16x8 v1 = *reinterpret_cast<const bf16x8*>(vp1);
        reinterpret_cast<bf16x8*>(Ks[0])[tid]       = k0;
        reinterpret_cast<bf16x8*>(Ks[0])[tid + 256] = k1;
        reinterpret_cast<bf16x8*>(Vs[0])[tid]       = v0;
        reinterpret_cast<bf16x8*>(Vs[0])[tid + 256] = v1;
    }
    __syncthreads();

    for (int jt = 0; jt <= qt; ++jt) {
        int buf = jt & 1;
        const u16* ksb = Ks[buf];
        const u16* vsb = Vs[buf];

        // (1) issue next tile's global loads — in flight during compute
        bf16x8 kpre0, kpre1, vpre0, vpre1;
        if (jt < qt) {
            kp0 += 64*HS_; kp1 += 64*HS_; vp0 += 64; vp1 += 64;
            kpre0 = *reinterpret_cast<const bf16x8*>(kp0);
            kpre1 = *reinterpret_cast<const bf16x8*>(kp1);
            vpre0 = *reinterpret_cast<const bf16x8*>(vp0);
            vpre1 = *reinterpret_cast<const bf16x8*>(vp1);
        }

        // (2) S = Q @ K^T
        f32x4 Sa[4] = {};
        #pragma unroll
        for (int nt = 0; nt < 4; ++nt) {
            bf16x8 bk0 = *reinterpret_cast<const bf16x8*>(ksb + rb0 + nt*1024);
            bf16x8 bk1 = *reinterpret_cast<const bf16x8*>(ksb + rb1 + nt*1024);
            Sa[nt] = __builtin_amdgcn_mfma_f32_16x16x32_bf16(qf[0], bk0, Sa[nt], 0, 0, 0);
            Sa[nt] = __builtin_amdgcn_mfma_f32_16x16x32_bf16(qf[1], bk1, Sa[nt], 0, 0, 0);
        }

        if (jt == qt) {   // causal mask in diagonal tile
            int kb = jt * 64;
            #pragma unroll
            for (int nt = 0; nt < 4; ++nt)
                #pragma unroll
                for (int r = 0; r < 4; ++r) {
                    int kg = kb + nt*16 + lr;
                    int qg = qw + quad*4 + r;
                    if (kg > qg) Sa[nt][r] = -INFINITY;
                }
        }

        // P = exp2(S); per-lane row sums; P -> per-wave LDS
        #pragma unroll
        for (int nt = 0; nt < 4; ++nt)
            #pragma unroll
            for (int r = 0; r < 4; ++r) {
                float pv = __builtin_amdgcn_exp2f(Sa[nt][r]);
                lrow[r] += pv;
                Psw[offw[nt][r]] = f2bf(pv);
            }

        // O += P @ V  (same-wave LDS ordering via lgkmcnt; no barrier)
        #pragma unroll
        for (int kk = 0; kk < 2; ++kk) {
            int rb = kk ? rb1 : rb0;
            bf16x8 pa = *reinterpret_cast<const bf16x8*>(Psw + rb);
            #pragma unroll
            for (int nt = 0; nt < 4; ++nt) {
                bf16x8 vb = *reinterpret_cast<const bf16x8*>(vsb + rb + nt*1024);
                Oa[nt] = __builtin_amdgcn_mfma_f32_16x16x32_bf16(pa, vb, Oa[nt], 0, 0, 0);
            }
        }

        // (3) stage next tile into the other buffer; single barrier
        if (jt < qt) {
            int nb = buf ^ 1;
            reinterpret_cast<bf16x8*>(Ks[nb])[tid]       = kpre0;
            reinterpret_cast<bf16x8*>(Ks[nb])[tid + 256] = kpre1;
            reinterpret_cast<bf16x8*>(Vs[nb])[tid]       = vpre0;
            reinterpret_cast<bf16x8*>(Vs[nb])[tid + 256] = vpre1;
            __syncthreads();
        }
    }

    // epilogue: reduce row sums across 16 col-lanes, normalize, store
    int b = bh >> 4, h = bh & 15;
    #pragma unroll
    for (int r = 0; r < 4; ++r) {
        float s = lrow[r];
        #pragma unroll
        for (int off = 8; off >= 1; off >>= 1)
            s += __shfl_xor(s, off, 64);
        float inv = 1.f / s;
        int qg = qw + quad*4 + r;
        #pragma unroll
        for (int nt = 0; nt < 4; ++nt) {
            int d = nt*16 + lr;
            Ob[((size_t)b*T_ + qg)*D_ + h*HS_ + d] = f2bf(Oa[nt][r] * inv);
        }
    }
}

extern "C" void kernel_launch(void* const* d_in, const int* in_sizes, int n_in,
                              void* d_out, int out_size, void* d_ws, size_t ws_size,
                              hipStream_t stream) {
    (void)in_sizes; (void)n_in; (void)out_size; (void)ws_size;
    const float* x     = (const float*)d_in[0];
    const float* w_qkv = (const float*)d_in[1];
    const float* b_qkv = (const float*)d_in[2];
    const float* w_out = (const float*)d_in[3];
    const float* b_out = (const float*)d_in[4];
    float* out = (float*)d_out;

    char* ws = (char*)d_ws;
    u16* Xb    = (u16*)ws; ws += (size_t)M_ * D_ * 2;
    u16* WqkvT = (u16*)ws; ws += (size_t)3 * D_ * D_ * 2;
    u16* WoutT = (u16*)ws; ws += (size_t)D_ * D_ * 2;
    u16* Qb    = (u16*)ws; ws += (size_t)M_ * D_ * 2;
    u16* Kb    = (u16*)ws; ws += (size_t)M_ * D_ * 2;
    u16* Vt    = (u16*)ws; ws += (size_t)M_ * D_ * 2;
    u16* Ob    = (u16*)ws; ws += (size_t)M_ * D_ * 2;

    prep_kernel<<<8192, 256, 0, stream>>>(x, w_qkv, w_out, Xb, WqkvT, WoutT);
    gemm_bt<0><<<dim3(M_/128, 3*D_/128), 256, 0, stream>>>(
        Xb, WqkvT, b_qkv, nullptr, Qb, Kb, Vt, M_, 3*D_, D_);
    attn_kernel<<<1024, 256, 0, stream>>>(Qb, Kb, Vt, Ob);
    gemm_bt<1><<<dim3(M_/128, D_/128), 256, 0, stream>>>(
        Ob, WoutT, b_out, out, nullptr, nullptr, nullptr, M_, D_, D_);
}